// Round 3
// baseline (269.628 us; speedup 1.0000x reference)
//
#include <hip/hip_runtime.h>

// Modular readout: 8 modules, each h = relu(x_m @ W1_m^T + b1_m); y_m = h @ W2_m^T + b2_m
// x [8192,4096] fp32; W1 [4096,4096] fp32 block-diag (8x 512x512); W2 [80,4096] fp32 block-diag
// out [8192,80] fp32 row-major (module-major columns).
//
// R3: R2 was latency-bound (occupancy: 112 VGPR + 128 AGPR -> 1 block/CU; MfmaUtil 14%).
//  - block 256 (4 waves), tile M=64 x N=256 (hidden halved): acc[4][4]=64 AGPR -> 3 blocks/CU.
//  - layer-2 partials combined via atomicAdd(out) after init kernel writes out = b2.
//  - W1 staged with global_load_lds(16B) from bf16 w1b (tier B, ws=4MB); x converted at staging.
//  - XOR swizzle slot = kq ^ ((row>>1)&3) on 16B chunks (A and B tiles): frag reads 2-way max.
//  - W2 converted inline in epilogue (no w2b buffer).

#define NMOD 8
#define DIM 512
#define OSZ 10
#define BATCH 8192
#define D_IN 4096
#define D_OUT 80
#define BM 64
#define BN 256
#define BK 32

typedef __attribute__((ext_vector_type(8))) short short8;   // 8 bf16 MFMA A/B frag
typedef __attribute__((ext_vector_type(4))) float float4v;  // MFMA C/D frag

__device__ __forceinline__ unsigned short f2bf(float f) {
    unsigned int u = __builtin_bit_cast(unsigned int, f);
    u += 0x7fffu + ((u >> 16) & 1u);   // RNE
    return (unsigned short)(u >> 16);
}

__device__ __forceinline__ short8 cvt8(float4 a, float4 b) {
    short8 r;
    r[0] = (short)f2bf(a.x); r[1] = (short)f2bf(a.y); r[2] = (short)f2bf(a.z); r[3] = (short)f2bf(a.w);
    r[4] = (short)f2bf(b.x); r[5] = (short)f2bf(b.y); r[6] = (short)f2bf(b.z); r[7] = (short)f2bf(b.w);
    return r;
}

// ------- init: out = broadcast b2 (atomic accumulation target) -------
__global__ void init_out_kernel(const float* __restrict__ b2, float* __restrict__ out) {
    int idx = blockIdx.x * 256 + threadIdx.x;            // 2560*256 = 655360 = 8192*80
    out[idx] = b2[idx % D_OUT];
}

// ------- tier B: gather W1 diag blocks -> w1b[8][512][512] bf16 (4 MB) -------
__global__ void cvt_w_kernel(const float* __restrict__ W1, ushort* __restrict__ w1b) {
    int j = blockIdx.x * 256 + threadIdx.x;              // 2048*256 = 524288 float4 jobs
    int mm = j >> 16, rem = j & 65535, r = rem >> 7, c4 = rem & 127;
    float4 v = *(const float4*)(W1 + (size_t)(mm * DIM + r) * D_IN + mm * DIM + c4 * 4);
    *(ushort4*)(w1b + (size_t)mm * DIM * DIM + r * DIM + c4 * 4) =
        make_ushort4(f2bf(v.x), f2bf(v.y), f2bf(v.z), f2bf(v.w));
}

// ---------------- fused kernel ----------------
// grid 2048 = (mtile*2 + half)*8 + m. block 256 (4 waves).
// Tile: 64 batch rows x 256 hidden cols (half of module's 512). Wave w: cols [w*64, w*64+64).
// LDS 32 KB: K-loop A[64][32]bf16 @0 (4K) + B[256][32]bf16 @4K (16K); epilogue ldsH[64][256] (32K, aliased).
template <bool WPRE>
__global__ __launch_bounds__(256, 3)
void fused_kernel(const float* __restrict__ x, const float* __restrict__ W1,
                  const ushort* __restrict__ w1b, const float* __restrict__ b1,
                  const float* __restrict__ W2, const float* __restrict__ b2,
                  float* __restrict__ out) {
    __shared__ ushort smem[16384];            // 32 KB
    ushort* ldsA = smem;                      // [64][32] swizzled
    ushort* ldsB = smem + 2048;               // [256][32] swizzled
    ushort* ldsH = smem;                      // [64][256] swizzled (epilogue alias)

    const int tid  = threadIdx.x;
    const int wave = tid >> 6;
    const int lane = tid & 63;
    const int r16  = lane & 15;
    const int kq   = lane >> 4;

    const int bid     = blockIdx.x;
    const int m       = bid & 7;              // module -> XCD round-robin
    const int t2      = bid >> 3;
    const int half    = t2 & 1;               // hidden half: cols [half*256, +256)
    const int rowBase = (t2 >> 1) * BM;

    const float*  xsrc = x + (size_t)rowBase * D_IN + m * DIM;                        // fp32
    const ushort* w1m  = w1b + (size_t)m * DIM * DIM + (size_t)half * BN * DIM;       // bf16 [256][512]
    const float*  w1f  = W1 + (size_t)(m * DIM + half * BN) * D_IN + m * DIM;         // fp32 fallback

    float4v acc[4][4];
#pragma unroll
    for (int i = 0; i < 4; i++)
#pragma unroll
        for (int j = 0; j < 4; j++) acc[i][j] = (float4v){0.f, 0.f, 0.f, 0.f};

    const int srow = tid >> 2;                // 0..63 staging row
    const int sg   = tid & 3;                 // global k-chunk (A path) / LDS slot (B DMA path)

    for (int kk = 0; kk < DIM / BK; kk++) {
        const int k0 = kk * BK;
        // ---- stage A: x fp32 -> bf16, 64x32, swizzled slot = g ^ ((row>>1)&3) ----
        {
            const int s = (srow >> 1) & 3;
            const float* p = xsrc + (size_t)srow * D_IN + k0 + sg * 8;
            *(short8*)(ldsA + srow * BK + (sg ^ s) * 8) = cvt8(*(const float4*)p, *(const float4*)(p + 4));
        }
        // ---- stage B: W1 256x32 ----
        if (WPRE) {
#pragma unroll
            for (int r = 0; r < 4; r++) {
                const int row = r * 64 + srow;
                const int s   = (row >> 1) & 3;
                // LDS slot (tid&3) holds global chunk (slot ^ s); dst is lane-contiguous.
                __builtin_amdgcn_global_load_lds(
                    (const __attribute__((address_space(1))) void*)(w1m + (size_t)row * DIM + k0 + (sg ^ s) * 8),
                    (__attribute__((address_space(3))) void*)(ldsB + row * BK + sg * 8), 16, 0, 0);
            }
        } else {
#pragma unroll
            for (int r = 0; r < 4; r++) {
                const int row = r * 64 + srow;
                const int s   = (row >> 1) & 3;
                const float* p = w1f + (size_t)row * D_IN + k0 + sg * 8;
                *(short8*)(ldsB + row * BK + (sg ^ s) * 8) = cvt8(*(const float4*)p, *(const float4*)(p + 4));
            }
        }
        __syncthreads();

        short8 aF[4], bF[4];
#pragma unroll
        for (int mt = 0; mt < 4; mt++) {
            const int row = mt * 16 + r16;
            aF[mt] = *(const short8*)(ldsA + row * BK + (kq ^ ((row >> 1) & 3)) * 8);
        }
#pragma unroll
        for (int nt = 0; nt < 4; nt++) {
            const int row = wave * 64 + nt * 16 + r16;
            bF[nt] = *(const short8*)(ldsB + row * BK + (kq ^ ((row >> 1) & 3)) * 8);
        }
#pragma unroll
        for (int mt = 0; mt < 4; mt++)
#pragma unroll
            for (int nt = 0; nt < 4; nt++)
                acc[mt][nt] = __builtin_amdgcn_mfma_f32_16x16x32_bf16(aF[mt], bF[nt], acc[mt][nt], 0, 0, 0);
        __syncthreads();
    }

    // ---- h (bias + relu) -> ldsH[64][256] bf16, col-XOR swizzle by row ----
    float b1v[4];
#pragma unroll
    for (int nt = 0; nt < 4; nt++)
        b1v[nt] = b1[m * DIM + half * BN + wave * 64 + nt * 16 + r16];

#pragma unroll
    for (int mt = 0; mt < 4; mt++) {
#pragma unroll
        for (int nt = 0; nt < 4; nt++) {
#pragma unroll
            for (int reg = 0; reg < 4; reg++) {
                float v = acc[mt][nt][reg] + b1v[nt];
                v = v > 0.f ? v : 0.f;
                const int lr  = mt * 16 + kq * 4 + reg;          // batch row (C row = quad*4+reg)
                const int col = wave * 64 + nt * 16 + r16;       // hidden col (within half)
                ldsH[lr * BN + (col ^ ((lr & 7) << 3))] = f2bf(v);
            }
        }
    }
    __syncthreads();

    // ---- layer 2 partial: y[64][10] += h[64][256] @ W2_half^T, all 4 waves (16 rows each) ----
    {
        float4v acc2 = (float4v){0.f, 0.f, 0.f, 0.f};
        const int hrow = wave * 16 + r16;                        // batch row (A operand m-index)
        const int hsw  = (hrow & 7) << 3;
        const float* w2row = W2 + (size_t)(m * OSZ + r16) * D_IN + m * DIM + half * BN;  // r16 = out col
#pragma unroll
        for (int kk2 = 0; kk2 < BN / 32; kk2++) {
            const int c = kk2 * 32 + kq * 8;
            short8 ha = *(const short8*)(ldsH + hrow * BN + (c ^ hsw));
            short8 wb = {0, 0, 0, 0, 0, 0, 0, 0};
            if (r16 < OSZ) {
                const float* p = w2row + c;
                wb = cvt8(*(const float4*)p, *(const float4*)(p + 4));
            }
            acc2 = __builtin_amdgcn_mfma_f32_16x16x32_bf16(ha, wb, acc2, 0, 0, 0);
        }
        if (r16 < OSZ) {
#pragma unroll
            for (int reg = 0; reg < 4; reg++) {
                const int grow = rowBase + wave * 16 + kq * 4 + reg;
                atomicAdd(out + (size_t)grow * D_OUT + m * OSZ + r16, acc2[reg]);
            }
        }
    }
}

extern "C" void kernel_launch(void* const* d_in, const int* in_sizes, int n_in,
                              void* d_out, int out_size, void* d_ws, size_t ws_size,
                              hipStream_t stream) {
    const float* x  = (const float*)d_in[0];
    const float* W1 = (const float*)d_in[1];
    const float* b1 = (const float*)d_in[2];
    const float* W2 = (const float*)d_in[3];
    const float* b2 = (const float*)d_in[4];
    float* out = (float*)d_out;

    init_out_kernel<<<dim3(2560), dim3(256), 0, stream>>>(b2, out);

    if (ws_size >= (size_t)NMOD * DIM * DIM * sizeof(ushort)) {   // 4 MB: tier B (bf16 W1 + DMA staging)
        ushort* w1b = (ushort*)d_ws;
        cvt_w_kernel<<<dim3(2048), dim3(256), 0, stream>>>(W1, w1b);
        fused_kernel<true><<<dim3(2048), dim3(256), 0, stream>>>(x, W1, w1b, b1, W2, b2, out);
    } else {                                                      // tier C: zero workspace
        fused_kernel<false><<<dim3(2048), dim3(256), 0, stream>>>(x, W1, nullptr, b1, W2, b2, out);
    }
}